// Round 9
// baseline (566.138 us; speedup 1.0000x reference)
//
#include <hip/hip_runtime.h>
#include <hip/hip_bf16.h>

typedef __attribute__((ext_vector_type(8))) short short8;
typedef __attribute__((ext_vector_type(4))) float floatx4;

__device__ __forceinline__ unsigned short f2bf(float x) {
  __hip_bfloat16 h = __float2bfloat16(x);
  return __builtin_bit_cast(unsigned short, h);
}

__device__ __forceinline__ float readlane_f(float v, int l) {
  return __builtin_bit_cast(float,
      __builtin_amdgcn_readlane(__builtin_bit_cast(int, v), l));
}

// ---------------------------------------------------------------------
// Build extended transposed weights: Bt[o][r], r = k*64+d for k<K2 (from
// W[k][d][o]), and r in [K2*64, K2*64+64) from root[d][o]. bf16.
// ---------------------------------------------------------------------
__global__ __launch_bounds__(256) void cvt_wext_kernel(
    const float* __restrict__ W, const float* __restrict__ root,
    unsigned short* __restrict__ Bt, int K2) {
  int R = (K2 + 1) * 64;
  int i = blockIdx.x * 256 + threadIdx.x;
  if (i >= 64 * R) return;
  int o = i / R, r = i - o * R;
  int k = r >> 6, d = r & 63;
  float v = (k < K2) ? W[(k << 12) + (d << 6) + o] : root[(d << 6) + o];
  Bt[(size_t)o * R + r] = f2bf(v);
}

// ---------------------------------------------------------------------
// CSR build: histogram -> scan -> cursor scatter
// ---------------------------------------------------------------------
__global__ __launch_bounds__(256) void zero_int_kernel(int* __restrict__ p, int n) {
  int i = blockIdx.x * 256 + threadIdx.x;
  if (i < n) p[i] = 0;
}

__global__ __launch_bounds__(256) void hist_kernel(
    const int* __restrict__ dst, int* __restrict__ deg, int nE) {
  int e = blockIdx.x * 256 + threadIdx.x;
  if (e < nE) atomicAdd(&deg[dst[e]], 1);
}

__global__ __launch_bounds__(256) void blocksum_kernel(
    const int* __restrict__ deg, int* __restrict__ partial, int N) {
  __shared__ int s[256];
  int t = threadIdx.x, i = blockIdx.x * 256 + t;
  s[t] = (i < N) ? deg[i] : 0;
  __syncthreads();
  for (int off = 128; off > 0; off >>= 1) {
    if (t < off) s[t] += s[t + off];
    __syncthreads();
  }
  if (t == 0) partial[blockIdx.x] = s[0];
}

// single-block exclusive scan of up to 256 partials (N <= 65536)
__global__ __launch_bounds__(256) void scanpartials_kernel(
    int* __restrict__ partial, int nb) {
  __shared__ int s[256];
  int t = threadIdx.x;
  int v = (t < nb) ? partial[t] : 0;
  s[t] = v;
  __syncthreads();
  for (int off = 1; off < 256; off <<= 1) {
    int x = (t >= off) ? s[t - off] : 0;
    __syncthreads();
    s[t] += x;
    __syncthreads();
  }
  if (t < nb) partial[t] = s[t] - v;
}

__global__ __launch_bounds__(256) void blockscan_kernel(
    const int* __restrict__ deg, const int* __restrict__ partial,
    int* __restrict__ row_start, int* __restrict__ cursor, int N, int nE) {
  __shared__ int s[256];
  int t = threadIdx.x, i = blockIdx.x * 256 + t;
  int v = (i < N) ? deg[i] : 0;
  s[t] = v;
  __syncthreads();
  for (int off = 1; off < 256; off <<= 1) {
    int x = (t >= off) ? s[t - off] : 0;
    __syncthreads();
    s[t] += x;
    __syncthreads();
  }
  if (i < N) {
    int excl = s[t] - v + partial[blockIdx.x];
    row_start[i] = excl;
    cursor[i] = excl;
  }
  if (i == 0) row_start[N] = nE;
}

__global__ __launch_bounds__(256) void scatter_kernel(
    const int* __restrict__ dst, int* __restrict__ cursor,
    int* __restrict__ eidx, int nE) {
  int e = blockIdx.x * 256 + threadIdx.x;
  if (e < nE) {
    int pos = atomicAdd(&cursor[dst[e]], 1);
    eidx[pos] = e;
  }
}

// ---------------------------------------------------------------------
// Z-build: one wave per dst node, lane o = channel o. Register buckets.
// Per edge, the spline cell (l0,l1) is WAVE-UNIFORM -> scalar-branch
// dispatch over (K-1)^2 cells; each cell does 2 mul + 4 fmac on
// statically-indexed registers (vs R7's 25 fma + 40 selects).
// Edge meta decoded per-lane then broadcast via v_readlane (src fits in
// 16 bits, N<=65536); no LDS at all. x-row gather pipelined 3 deep off
// scalar bases.
// ---------------------------------------------------------------------
template <int K, int K2>
__global__ __launch_bounds__(256) void zbuild_kernel(
    const int* __restrict__ eidx, const int* __restrict__ row_start,
    const int* __restrict__ src, const float* __restrict__ attr,
    const float* __restrict__ X, unsigned short* __restrict__ Z, int N) {
  constexpr int R = (K2 + 1) * 64;
  const int t = threadIdx.x, w = t >> 6, o = t & 63;
  const int node = blockIdx.x * 4 + w;
  if (node >= N) return;

  float acc[K2];
#pragma unroll
  for (int k = 0; k < K2; ++k) acc[k] = 0.f;

  const int beg = row_start[node], end = row_start[node + 1];
  for (int c0 = beg; c0 < end; c0 += 64) {
    const int m = min(64, end - c0);
    // per-lane meta for edge (c0 + o): pack src | cell<<16
    float vF0 = 0.f, vF1 = 0.f;
    int vMeta = 0;
    if (o < m) {
      int e = eidx[c0 + o];
      float2 a = *(const float2*)&attr[2 * e];
      int s = src[e];
      float u = a.x * (float)(K - 1);
      float v = a.y * (float)(K - 1);
      int l0 = min((int)u, K - 2);   // u in [0,K-1); exact clip-equivalent
      int l1 = min((int)v, K - 2);
      vF0 = u - (float)l0;
      vF1 = v - (float)l1;
      vMeta = s | ((l0 + l1 * (K - 1)) << 16);
    }
    // prefetch pipeline (depth 3) off readlane-broadcast scalar bases
    float x0 = 0.f, x1 = 0.f, x2 = 0.f;
    if (m > 0) x0 = X[(size_t)(__builtin_amdgcn_readlane(vMeta, 0) & 0xFFFF) * 64 + o];
    if (m > 1) x1 = X[(size_t)(__builtin_amdgcn_readlane(vMeta, 1) & 0xFFFF) * 64 + o];
    if (m > 2) x2 = X[(size_t)(__builtin_amdgcn_readlane(vMeta, 2) & 0xFFFF) * 64 + o];

    for (int j = 0; j < m; ++j) {
      float xn = 0.f;
      if (j + 3 < m)
        xn = X[(size_t)(__builtin_amdgcn_readlane(vMeta, j + 3) & 0xFFFF) * 64 + o];
      int cell = __builtin_amdgcn_readfirstlane(
          __builtin_amdgcn_readlane(vMeta, j)) >> 16;
      float f0 = readlane_f(vF0, j);
      float f1 = readlane_f(vF1, j);
      float c0f = 1.f - f0;
      float cx = (1.f - f1) * x0;
      float dx = f1 * x0;
#pragma unroll
      for (int L1 = 0; L1 < K - 1; ++L1)
#pragma unroll
        for (int L0 = 0; L0 < K - 1; ++L0)
          if (cell == L0 + L1 * (K - 1)) {   // uniform scalar branch
            acc[L0 + L1 * K]           += c0f * cx;
            acc[L0 + 1 + L1 * K]       += f0 * cx;
            acc[L0 + (L1 + 1) * K]     += c0f * dx;
            acc[L0 + 1 + (L1 + 1) * K] += f0 * dx;
          }
      x0 = x1; x1 = x2; x2 = xn;
    }
  }

  const int deg = end - beg;
  const float inv = 1.f / (float)max(deg, 1);
  unsigned short* zr = Z + (size_t)node * R;
#pragma unroll
  for (int k = 0; k < K2; ++k) zr[k * 64 + o] = f2bf(acc[k] * inv);
  zr[K2 * 64 + o] = f2bf(X[(size_t)node * 64 + o]);
}

// ---------------------------------------------------------------------
// Fused GEMM: out[n,o] = ELU( Zext[n,:] @ Bt[o,:] + bias[o] )  (bf16 MFMA)
// Zext row-major [N x R], Bt row-major [64 x R], R = KC*64.
// ---------------------------------------------------------------------
template <int KC>
__global__ __launch_bounds__(256) void gemm_fused_kernel(
    const unsigned short* __restrict__ Z, const unsigned short* __restrict__ Bt,
    const float* __restrict__ bias, float* __restrict__ out, int N) {
  constexpr int R = KC * 64;
  __shared__ unsigned short As[64 * 72];
  __shared__ unsigned short Bs[64 * 72];
  const int t = threadIdx.x, w = t >> 6, lane = t & 63;
  const int mrow = lane & 15, q = lane >> 4;
  const int n0 = blockIdx.x * 64;

  floatx4 acc[4] = {{0,0,0,0},{0,0,0,0},{0,0,0,0},{0,0,0,0}};

  for (int kc = 0; kc < KC; ++kc) {
    __syncthreads();
    for (int i = t; i < 512; i += 256) {
      int row = i >> 3, cg = i & 7;
      int n = n0 + row;
      float4 val = make_float4(0.f, 0.f, 0.f, 0.f);
      if (n < N) val = *(const float4*)&Z[(size_t)n * R + kc * 64 + cg * 8];
      *(float4*)&As[row * 72 + cg * 8] = val;
    }
    for (int i = t; i < 512; i += 256) {
      int row = i >> 3, cg = i & 7;
      *(float4*)&Bs[row * 72 + cg * 8] =
          *(const float4*)&Bt[(size_t)row * R + kc * 64 + cg * 8];
    }
    __syncthreads();

    short8 a0 = *(const short8*)&As[(w * 16 + mrow) * 72 + q * 8];
    short8 a1 = *(const short8*)&As[(w * 16 + mrow) * 72 + 32 + q * 8];
#pragma unroll
    for (int ot = 0; ot < 4; ++ot) {
      short8 b0 = *(const short8*)&Bs[(ot * 16 + mrow) * 72 + q * 8];
      short8 b1 = *(const short8*)&Bs[(ot * 16 + mrow) * 72 + 32 + q * 8];
      acc[ot] = __builtin_amdgcn_mfma_f32_16x16x32_bf16(a0, b0, acc[ot], 0, 0, 0);
      acc[ot] = __builtin_amdgcn_mfma_f32_16x16x32_bf16(a1, b1, acc[ot], 0, 0, 0);
    }
  }

  // epilogue: D layout col(o)=ot*16+mrow, row(node)=q*4+r
#pragma unroll
  for (int ot = 0; ot < 4; ++ot) {
    float b = bias[ot * 16 + mrow];
#pragma unroll
    for (int r = 0; r < 4; ++r) {
      int node = n0 + w * 16 + q * 4 + r;
      if (node < N) {
        float v = acc[ot][r] + b;
        v = v > 0.f ? v : (expf(v) - 1.f);
        out[(size_t)node * 64 + ot * 16 + mrow] = v;
      }
    }
  }
}

// ---------------------------------------------------------------------
// dense layer (fp32 VALU): out = act(X@Wm + b); ACT 1=ReLU
// ---------------------------------------------------------------------
template <int ACT>
__global__ __launch_bounds__(256) void node_dense_kernel(
    const float* __restrict__ X, const float* __restrict__ Wm,
    const float* __restrict__ bias, float* __restrict__ out, int N) {
  __shared__ float Ws[64 * 64];
  __shared__ float XsT[64 * 132];
  const int t = threadIdx.x;
  const int n0 = blockIdx.x * 128;

  for (int i = t; i < 1024; i += 256)
    ((float4*)Ws)[i] = ((const float4*)Wm)[i];
  for (int i = t; i < 8192; i += 256) {
    int nl = i >> 6, d = i & 63;
    int n = n0 + nl;
    XsT[d * 132 + nl] = (n < N) ? X[(size_t)n * 64 + d] : 0.f;
  }
  __syncthreads();

  const int o = t & 63, ng = t >> 6;
  float acc[32];
#pragma unroll
  for (int j = 0; j < 32; ++j) acc[j] = 0.f;

  for (int d = 0; d < 64; ++d) {
    float w = Ws[d * 64 + o];
    const float4* xp = (const float4*)&XsT[d * 132 + ng * 32];
#pragma unroll
    for (int j4 = 0; j4 < 8; ++j4) {
      float4 xv = xp[j4];
      acc[j4 * 4 + 0] += xv.x * w;
      acc[j4 * 4 + 1] += xv.y * w;
      acc[j4 * 4 + 2] += xv.z * w;
      acc[j4 * 4 + 3] += xv.w * w;
    }
  }

  float b = bias[o];
#pragma unroll
  for (int j = 0; j < 32; ++j) {
    int n = n0 + ng * 32 + j;
    if (n >= N) continue;
    float v = acc[j] + b;
    if (ACT == 0) v = v > 0.f ? v : (expf(v) - 1.f);
    else          v = v > 0.f ? v : 0.f;
    out[(size_t)n * 64 + o] = v;
  }
}

// ---------------------------------------------------------------------
// final projection D=64 -> C=8 with ReLU
// ---------------------------------------------------------------------
__global__ __launch_bounds__(256) void mlp2_kernel(
    const float* __restrict__ X, const float* __restrict__ W,
    const float* __restrict__ bias, float* __restrict__ out, int N) {
  __shared__ float Ws[512];
  __shared__ float bs[8];
  __shared__ float Xs[32 * 64];
  int t = threadIdx.x;
  int n0 = blockIdx.x * 32;
  if (t < 8) bs[t] = bias[t];
  for (int i = t; i < 512; i += 256) Ws[i] = W[i];
  for (int i = t; i < 512; i += 256) {
    int n = n0 + (i >> 4);
    ((float4*)Xs)[i] = (n < N) ? ((const float4*)(X + (size_t)n * 64))[i & 15]
                               : make_float4(0.f, 0.f, 0.f, 0.f);
  }
  __syncthreads();
  int c = t & 7, nl = t >> 3;
  float acc = bs[c];
  for (int d = 0; d < 64; ++d) acc += Xs[nl * 64 + d] * Ws[d * 8 + c];
  int n = n0 + nl;
  if (n < N) out[(size_t)n * 8 + c] = acc > 0.f ? acc : 0.f;
}

// ---------------------------------------------------------------------
extern "C" void kernel_launch(void* const* d_in, const int* in_sizes, int n_in,
                              void* d_out, int out_size, void* d_ws, size_t ws_size,
                              hipStream_t stream) {
  const float* x     = (const float*)d_in[0];
  const int*   ei    = (const int*)d_in[1];
  const float* attr  = (const float*)d_in[2];
  const float* W1    = (const float*)d_in[3];
  const float* root1 = (const float*)d_in[4];
  const float* b1    = (const float*)d_in[5];
  const float* W2    = (const float*)d_in[6];
  const float* root2 = (const float*)d_in[7];
  const float* b2    = (const float*)d_in[8];
  const float* m1w   = (const float*)d_in[9];
  const float* m1b   = (const float*)d_in[10];
  const float* m2w   = (const float*)d_in[11];
  const float* m2b   = (const float*)d_in[12];

  const int N  = in_sizes[0] / 64;
  const int nE = in_sizes[1] / 2;
  const int* src  = ei;
  const int* dstv = ei + nE;
  float* out = (float*)d_out;

  // workspace layout
  float* h1 = (float*)d_ws;                 // N*64
  float* h2 = h1 + (size_t)N * 64;          // N*64
  float* t1 = h2 + (size_t)N * 64;          // N*64
  int* deg       = (int*)(t1 + (size_t)N * 64);
  int* row_start = deg + N;
  int* cursor    = row_start + (N + 1);
  int* eidx      = cursor + N;
  int* partial   = eidx + nE;               // 256
  char* pbase = (char*)(partial + 256);
  pbase = (char*)(((uintptr_t)pbase + 15) & ~(uintptr_t)15);
  unsigned short* Bt1 = (unsigned short*)pbase;       // 64 * 640
  unsigned short* Bt2 = Bt1 + 64 * 640;               // 64 * 1664
  unsigned short* Z   = Bt2 + 64 * 1664;              // N * 1664

  dim3 blk(256);
  int nbN  = (N + 255) / 256;
  int nbE  = (nE + 255) / 256;
  int nbZ  = (N + 3) / 4;
  int nbG  = (N + 63) / 64;
  int nb128 = (N + 127) / 128;

  // ----- CSR build (graph identical both layers) -----
  zero_int_kernel<<<nbN, blk, 0, stream>>>(deg, N);
  hist_kernel<<<nbE, blk, 0, stream>>>(dstv, deg, nE);
  blocksum_kernel<<<nbN, blk, 0, stream>>>(deg, partial, N);
  scanpartials_kernel<<<1, blk, 0, stream>>>(partial, nbN);
  blockscan_kernel<<<nbN, blk, 0, stream>>>(deg, partial, row_start, cursor, N, nE);
  scatter_kernel<<<nbE, blk, 0, stream>>>(dstv, cursor, eidx, nE);

  // ----- weight prep -----
  cvt_wext_kernel<<<(64 * 640 + 255) / 256, blk, 0, stream>>>(W1, root1, Bt1, 9);
  cvt_wext_kernel<<<(64 * 1664 + 255) / 256, blk, 0, stream>>>(W2, root2, Bt2, 25);

  // ----- layer 1 (K=3, K2=9, R=640) -----
  zbuild_kernel<3, 9><<<nbZ, blk, 0, stream>>>(eidx, row_start, src, attr, x, Z, N);
  gemm_fused_kernel<10><<<nbG, blk, 0, stream>>>(Z, Bt1, b1, h1, N);

  // ----- layer 2 (K=5, K2=25, R=1664) -----
  zbuild_kernel<5, 25><<<nbZ, blk, 0, stream>>>(eidx, row_start, src, attr, h1, Z, N);
  gemm_fused_kernel<26><<<nbG, blk, 0, stream>>>(Z, Bt2, b2, h2, N);

  // ----- MLP head -----
  node_dense_kernel<1><<<nb128, blk, 0, stream>>>(h2, m1w, m1b, t1, N);
  mlp2_kernel<<<(N + 31) / 32, blk, 0, stream>>>(t1, m2w, m2b, out, N);
}

// Round 10
// 445.159 us; speedup vs baseline: 1.2718x; 1.2718x over previous
//
#include <hip/hip_runtime.h>
#include <hip/hip_bf16.h>

typedef __attribute__((ext_vector_type(8))) short short8;
typedef __attribute__((ext_vector_type(4))) float floatx4;
typedef __attribute__((ext_vector_type(16))) float floatx16;

__device__ __forceinline__ unsigned short f2bf(float x) {
  __hip_bfloat16 h = __float2bfloat16(x);
  return __builtin_bit_cast(unsigned short, h);
}

// ---------------------------------------------------------------------
// X (fp32) -> bf16 copy
// ---------------------------------------------------------------------
__global__ __launch_bounds__(256) void cvt_x_kernel(
    const float* __restrict__ X, unsigned short* __restrict__ Xbf, int n) {
  int i = blockIdx.x * 256 + threadIdx.x;
  if (i < n) Xbf[i] = f2bf(X[i]);
}

// ---------------------------------------------------------------------
// Build extended transposed weights: Bt[o][r], r = k*64+d for k<K2 (from
// W[k][d][o]), and r in [K2*64, K2*64+64) from root[d][o]. bf16.
// ---------------------------------------------------------------------
__global__ __launch_bounds__(256) void cvt_wext_kernel(
    const float* __restrict__ W, const float* __restrict__ root,
    unsigned short* __restrict__ Bt, int K2) {
  int R = (K2 + 1) * 64;
  int i = blockIdx.x * 256 + threadIdx.x;
  if (i >= 64 * R) return;
  int o = i / R, r = i - o * R;
  int k = r >> 6, d = r & 63;
  float v = (k < K2) ? W[(k << 12) + (d << 6) + o] : root[(d << 6) + o];
  Bt[(size_t)o * R + r] = f2bf(v);
}

// ---------------------------------------------------------------------
// CSR build: histogram -> scan -> cursor scatter
// ---------------------------------------------------------------------
__global__ __launch_bounds__(256) void zero_int_kernel(int* __restrict__ p, int n) {
  int i = blockIdx.x * 256 + threadIdx.x;
  if (i < n) p[i] = 0;
}

__global__ __launch_bounds__(256) void hist_kernel(
    const int* __restrict__ dst, int* __restrict__ deg, int nE) {
  int e = blockIdx.x * 256 + threadIdx.x;
  if (e < nE) atomicAdd(&deg[dst[e]], 1);
}

__global__ __launch_bounds__(256) void blocksum_kernel(
    const int* __restrict__ deg, int* __restrict__ partial, int N) {
  __shared__ int s[256];
  int t = threadIdx.x, i = blockIdx.x * 256 + t;
  s[t] = (i < N) ? deg[i] : 0;
  __syncthreads();
  for (int off = 128; off > 0; off >>= 1) {
    if (t < off) s[t] += s[t + off];
    __syncthreads();
  }
  if (t == 0) partial[blockIdx.x] = s[0];
}

__global__ __launch_bounds__(256) void scanpartials_kernel(
    int* __restrict__ partial, int nb) {
  __shared__ int s[256];
  int t = threadIdx.x;
  int v = (t < nb) ? partial[t] : 0;
  s[t] = v;
  __syncthreads();
  for (int off = 1; off < 256; off <<= 1) {
    int x = (t >= off) ? s[t - off] : 0;
    __syncthreads();
    s[t] += x;
    __syncthreads();
  }
  if (t < nb) partial[t] = s[t] - v;
}

__global__ __launch_bounds__(256) void blockscan_kernel(
    const int* __restrict__ deg, const int* __restrict__ partial,
    int* __restrict__ row_start, int* __restrict__ cursor, int N, int nE) {
  __shared__ int s[256];
  int t = threadIdx.x, i = blockIdx.x * 256 + t;
  int v = (i < N) ? deg[i] : 0;
  s[t] = v;
  __syncthreads();
  for (int off = 1; off < 256; off <<= 1) {
    int x = (t >= off) ? s[t - off] : 0;
    __syncthreads();
    s[t] += x;
    __syncthreads();
  }
  if (i < N) {
    int excl = s[t] - v + partial[blockIdx.x];
    row_start[i] = excl;
    cursor[i] = excl;
  }
  if (i == 0) row_start[N] = nE;
}

__global__ __launch_bounds__(256) void scatter_kernel(
    const int* __restrict__ dst, int* __restrict__ cursor,
    int* __restrict__ eidx, int nE) {
  int e = blockIdx.x * 256 + threadIdx.x;
  if (e < nE) {
    int pos = atomicAdd(&cursor[dst[e]], 1);
    eidx[pos] = e;
  }
}

// ---------------------------------------------------------------------
// Z-build via MFMA: one wave per dst node. Per 16-edge chunk:
//   D[bucket][ch] += A[bucket][edge] * B[edge][ch]     (32x32x16 bf16 MFMA x2)
// A = basis coefficients (wave computes from edge meta), B = gathered bf16
// x-rows. D accumulates in regs across chunks. Layouts (gfx950):
//   A: m=lane&31, k=(lane>>5)*8+j   B: n=lane&31, k=(lane>>5)*8+j
//   D: col=lane&31, row=(reg&3)+8*(reg>>2)+4*(lane>>5)
// Padded edges: l=127 sentinel -> coeff 0. Rows >= K2: mi=-3 -> coeff 0.
// ---------------------------------------------------------------------
template <int K, int K2>
__global__ __launch_bounds__(256) void zbuild_kernel(
    const int* __restrict__ eidx, const int* __restrict__ row_start,
    const int* __restrict__ src, const float* __restrict__ attr,
    const unsigned short* __restrict__ Xbf, unsigned short* __restrict__ Z,
    int N) {
  constexpr int R = (K2 + 1) * 64;
  __shared__ float4 sMeta[4][16];    // per wave: f0, f1, l0|l1<<8, elem-offset
  const int t = threadIdx.x, w = t >> 6, lane = t & 63;
  const int node = blockIdx.x * 4 + w;
  if (node >= N) return;   // wave-uniform; no __syncthreads in this kernel

  const int col = lane & 31;     // A: bucket row m  /  B: channel col n
  const int half = lane >> 5;    // k-half
  const int mi0 = (col < K2) ? (col % K) : -3;
  const int mi1 = (col < K2) ? (col / K) : -3;

  floatx16 d0, d1;
#pragma unroll
  for (int i = 0; i < 16; ++i) { d0[i] = 0.f; d1[i] = 0.f; }

  const int beg = row_start[node], end = row_start[node + 1];
  for (int c0 = beg; c0 < end; c0 += 16) {
    const int m = min(16, end - c0);
    if (lane < 16) {
      float f0 = 0.f, f1 = 0.f;
      int lpack = 0x7F7F, off = 0;
      if (lane < m) {
        int e = eidx[c0 + lane];
        float2 a = *(const float2*)&attr[2 * e];
        int s = src[e];
        float u = a.x * (float)(K - 1);
        float v = a.y * (float)(K - 1);
        int l0 = min((int)u, K - 2);   // exact clip-equivalent for u in [0,K-1)
        int l1 = min((int)v, K - 2);
        f0 = u - (float)l0;
        f1 = v - (float)l1;
        lpack = l0 | (l1 << 8);
        off = s * 64;
      }
      sMeta[w][lane] = make_float4(f0, f1, __builtin_bit_cast(float, lpack),
                                   __builtin_bit_cast(float, off));
    }
    // same-wave LDS write->read (lockstep; compiler inserts lgkmcnt)
    short8 A, Blo, Bhi;
#pragma unroll
    for (int j = 0; j < 8; ++j) {
      float4 md = sMeta[w][half * 8 + j];
      int lp = __builtin_bit_cast(int, md.z);
      int off = __builtin_bit_cast(int, md.w);
      int l0 = lp & 0xFF, l1 = (lp >> 8) & 0xFF;
      float su = (mi0 == l0) ? (1.f - md.x) : ((mi0 == l0 + 1) ? md.x : 0.f);
      float sv = (mi1 == l1) ? (1.f - md.y) : ((mi1 == l1 + 1) ? md.y : 0.f);
      A[j] = (short)f2bf(su * sv);
      Blo[j] = (short)Xbf[off + col];
      Bhi[j] = (short)Xbf[off + 32 + col];
    }
    d0 = __builtin_amdgcn_mfma_f32_32x32x16_bf16(A, Blo, d0, 0, 0, 0);
    d1 = __builtin_amdgcn_mfma_f32_32x32x16_bf16(A, Bhi, d1, 0, 0, 0);
  }

  const int deg = end - beg;
  const float inv = 1.f / (float)max(deg, 1);
  unsigned short* zr = Z + (size_t)node * R;
#pragma unroll
  for (int reg = 0; reg < 16; ++reg) {
    int r = (reg & 3) + 8 * (reg >> 2) + 4 * half;
    if (r < K2) {
      zr[r * 64 + col]      = f2bf(d0[reg] * inv);
      zr[r * 64 + 32 + col] = f2bf(d1[reg] * inv);
    }
  }
  zr[K2 * 64 + lane] = Xbf[node * 64 + lane];   // root-concat row
}

// ---------------------------------------------------------------------
// Fused GEMM: out[n,o] = ELU( Zext[n,:] @ Bt[o,:] + bias[o] )  (bf16 MFMA)
// OUTBF=1 -> bf16 output (feeds next zbuild), else fp32.
// ---------------------------------------------------------------------
template <int KC, int OUTBF>
__global__ __launch_bounds__(256) void gemm_fused_kernel(
    const unsigned short* __restrict__ Z, const unsigned short* __restrict__ Bt,
    const float* __restrict__ bias, void* __restrict__ outv, int N) {
  constexpr int R = KC * 64;
  __shared__ unsigned short As[64 * 72];
  __shared__ unsigned short Bs[64 * 72];
  const int t = threadIdx.x, w = t >> 6, lane = t & 63;
  const int mrow = lane & 15, q = lane >> 4;
  const int n0 = blockIdx.x * 64;

  floatx4 acc[4] = {{0,0,0,0},{0,0,0,0},{0,0,0,0},{0,0,0,0}};

  for (int kc = 0; kc < KC; ++kc) {
    __syncthreads();
    for (int i = t; i < 512; i += 256) {
      int row = i >> 3, cg = i & 7;
      int n = n0 + row;
      float4 val = make_float4(0.f, 0.f, 0.f, 0.f);
      if (n < N) val = *(const float4*)&Z[(size_t)n * R + kc * 64 + cg * 8];
      *(float4*)&As[row * 72 + cg * 8] = val;
    }
    for (int i = t; i < 512; i += 256) {
      int row = i >> 3, cg = i & 7;
      *(float4*)&Bs[row * 72 + cg * 8] =
          *(const float4*)&Bt[(size_t)row * R + kc * 64 + cg * 8];
    }
    __syncthreads();

    short8 a0 = *(const short8*)&As[(w * 16 + mrow) * 72 + q * 8];
    short8 a1 = *(const short8*)&As[(w * 16 + mrow) * 72 + 32 + q * 8];
#pragma unroll
    for (int ot = 0; ot < 4; ++ot) {
      short8 b0 = *(const short8*)&Bs[(ot * 16 + mrow) * 72 + q * 8];
      short8 b1 = *(const short8*)&Bs[(ot * 16 + mrow) * 72 + 32 + q * 8];
      acc[ot] = __builtin_amdgcn_mfma_f32_16x16x32_bf16(a0, b0, acc[ot], 0, 0, 0);
      acc[ot] = __builtin_amdgcn_mfma_f32_16x16x32_bf16(a1, b1, acc[ot], 0, 0, 0);
    }
  }

  // epilogue: D layout col(o)=ot*16+mrow, row(node)=q*4+r
#pragma unroll
  for (int ot = 0; ot < 4; ++ot) {
    float b = bias[ot * 16 + mrow];
#pragma unroll
    for (int r = 0; r < 4; ++r) {
      int node = n0 + w * 16 + q * 4 + r;
      if (node < N) {
        float v = acc[ot][r] + b;
        v = v > 0.f ? v : (expf(v) - 1.f);
        if (OUTBF)
          ((unsigned short*)outv)[(size_t)node * 64 + ot * 16 + mrow] = f2bf(v);
        else
          ((float*)outv)[(size_t)node * 64 + ot * 16 + mrow] = v;
      }
    }
  }
}

// ---------------------------------------------------------------------
// dense layer (fp32 VALU): out = act(X@Wm + b); ACT 1=ReLU
// ---------------------------------------------------------------------
template <int ACT>
__global__ __launch_bounds__(256) void node_dense_kernel(
    const float* __restrict__ X, const float* __restrict__ Wm,
    const float* __restrict__ bias, float* __restrict__ out, int N) {
  __shared__ float Ws[64 * 64];
  __shared__ float XsT[64 * 132];
  const int t = threadIdx.x;
  const int n0 = blockIdx.x * 128;

  for (int i = t; i < 1024; i += 256)
    ((float4*)Ws)[i] = ((const float4*)Wm)[i];
  for (int i = t; i < 8192; i += 256) {
    int nl = i >> 6, d = i & 63;
    int n = n0 + nl;
    XsT[d * 132 + nl] = (n < N) ? X[(size_t)n * 64 + d] : 0.f;
  }
  __syncthreads();

  const int o = t & 63, ng = t >> 6;
  float acc[32];
#pragma unroll
  for (int j = 0; j < 32; ++j) acc[j] = 0.f;

  for (int d = 0; d < 64; ++d) {
    float w = Ws[d * 64 + o];
    const float4* xp = (const float4*)&XsT[d * 132 + ng * 32];
#pragma unroll
    for (int j4 = 0; j4 < 8; ++j4) {
      float4 xv = xp[j4];
      acc[j4 * 4 + 0] += xv.x * w;
      acc[j4 * 4 + 1] += xv.y * w;
      acc[j4 * 4 + 2] += xv.z * w;
      acc[j4 * 4 + 3] += xv.w * w;
    }
  }

  float b = bias[o];
#pragma unroll
  for (int j = 0; j < 32; ++j) {
    int n = n0 + ng * 32 + j;
    if (n >= N) continue;
    float v = acc[j] + b;
    if (ACT == 0) v = v > 0.f ? v : (expf(v) - 1.f);
    else          v = v > 0.f ? v : 0.f;
    out[(size_t)n * 64 + o] = v;
  }
}

// ---------------------------------------------------------------------
// final projection D=64 -> C=8 with ReLU
// ---------------------------------------------------------------------
__global__ __launch_bounds__(256) void mlp2_kernel(
    const float* __restrict__ X, const float* __restrict__ W,
    const float* __restrict__ bias, float* __restrict__ out, int N) {
  __shared__ float Ws[512];
  __shared__ float bs[8];
  __shared__ float Xs[32 * 64];
  int t = threadIdx.x;
  int n0 = blockIdx.x * 32;
  if (t < 8) bs[t] = bias[t];
  for (int i = t; i < 512; i += 256) Ws[i] = W[i];
  for (int i = t; i < 512; i += 256) {
    int n = n0 + (i >> 4);
    ((float4*)Xs)[i] = (n < N) ? ((const float4*)(X + (size_t)n * 64))[i & 15]
                               : make_float4(0.f, 0.f, 0.f, 0.f);
  }
  __syncthreads();
  int c = t & 7, nl = t >> 3;
  float acc = bs[c];
  for (int d = 0; d < 64; ++d) acc += Xs[nl * 64 + d] * Ws[d * 8 + c];
  int n = n0 + nl;
  if (n < N) out[(size_t)n * 8 + c] = acc > 0.f ? acc : 0.f;
}

// ---------------------------------------------------------------------
extern "C" void kernel_launch(void* const* d_in, const int* in_sizes, int n_in,
                              void* d_out, int out_size, void* d_ws, size_t ws_size,
                              hipStream_t stream) {
  const float* x     = (const float*)d_in[0];
  const int*   ei    = (const int*)d_in[1];
  const float* attr  = (const float*)d_in[2];
  const float* W1    = (const float*)d_in[3];
  const float* root1 = (const float*)d_in[4];
  const float* b1    = (const float*)d_in[5];
  const float* W2    = (const float*)d_in[6];
  const float* root2 = (const float*)d_in[7];
  const float* b2    = (const float*)d_in[8];
  const float* m1w   = (const float*)d_in[9];
  const float* m1b   = (const float*)d_in[10];
  const float* m2w   = (const float*)d_in[11];
  const float* m2b   = (const float*)d_in[12];

  const int N  = in_sizes[0] / 64;
  const int nE = in_sizes[1] / 2;
  const int* src  = ei;
  const int* dstv = ei + nE;
  float* out = (float*)d_out;

  // workspace layout
  float* h2 = (float*)d_ws;                 // N*64 fp32
  float* t1 = h2 + (size_t)N * 64;          // N*64 fp32
  int* deg       = (int*)(t1 + (size_t)N * 64);
  int* row_start = deg + N;
  int* cursor    = row_start + (N + 1);
  int* eidx      = cursor + N;
  int* partial   = eidx + nE;               // 256
  char* pbase = (char*)(partial + 256);
  pbase = (char*)(((uintptr_t)pbase + 15) & ~(uintptr_t)15);
  unsigned short* Xbf  = (unsigned short*)pbase;      // N*64 bf16
  unsigned short* h1bf = Xbf + (size_t)N * 64;        // N*64 bf16
  unsigned short* Bt1  = h1bf + (size_t)N * 64;       // 64 * 640
  unsigned short* Bt2  = Bt1 + 64 * 640;              // 64 * 1664
  unsigned short* Z    = Bt2 + 64 * 1664;             // N * 1664

  dim3 blk(256);
  int nbN  = (N + 255) / 256;
  int nbE  = (nE + 255) / 256;
  int nbZ  = (N + 3) / 4;
  int nbG  = (N + 63) / 64;
  int nb128 = (N + 127) / 128;

  // ----- CSR build (graph identical both layers) -----
  zero_int_kernel<<<nbN, blk, 0, stream>>>(deg, N);
  hist_kernel<<<nbE, blk, 0, stream>>>(dstv, deg, nE);
  blocksum_kernel<<<nbN, blk, 0, stream>>>(deg, partial, N);
  scanpartials_kernel<<<1, blk, 0, stream>>>(partial, nbN);
  blockscan_kernel<<<nbN, blk, 0, stream>>>(deg, partial, row_start, cursor, N, nE);
  scatter_kernel<<<nbE, blk, 0, stream>>>(dstv, cursor, eidx, nE);

  // ----- weight / input prep -----
  cvt_wext_kernel<<<(64 * 640 + 255) / 256, blk, 0, stream>>>(W1, root1, Bt1, 9);
  cvt_wext_kernel<<<(64 * 1664 + 255) / 256, blk, 0, stream>>>(W2, root2, Bt2, 25);
  cvt_x_kernel<<<(N * 64 + 255) / 256, blk, 0, stream>>>(x, Xbf, N * 64);

  // ----- layer 1 (K=3, K2=9, R=640) -----
  zbuild_kernel<3, 9><<<nbZ, blk, 0, stream>>>(eidx, row_start, src, attr, Xbf, Z, N);
  gemm_fused_kernel<10, 1><<<nbG, blk, 0, stream>>>(Z, Bt1, b1, h1bf, N);

  // ----- layer 2 (K=5, K2=25, R=1664) -----
  zbuild_kernel<5, 25><<<nbZ, blk, 0, stream>>>(eidx, row_start, src, attr, h1bf, Z, N);
  gemm_fused_kernel<26, 0><<<nbG, blk, 0, stream>>>(Z, Bt2, b2, h2, N);

  // ----- MLP head -----
  node_dense_kernel<1><<<nb128, blk, 0, stream>>>(h2, m1w, m1b, t1, N);
  mlp2_kernel<<<(N + 31) / 32, blk, 0, stream>>>(t1, m2w, m2b, out, N);
}